// Round 1
// baseline (182.005 us; speedup 1.0000x reference)
//
#include <hip/hip_runtime.h>
#include <hip/hip_bf16.h>

typedef __attribute__((ext_vector_type(8))) short bf16x8;
typedef __attribute__((ext_vector_type(4))) float f32x4;

#define L_SEQ 512
#define N_IN 12
#define S_DIM 128
#define M_OUT 12

#define A_STRIDE 136   // bf16 elems; 272B row stride -> 2-way max on ds_read_b128
#define X_STRIDE 72    // bf16 elems; 144B row stride, 16B-aligned

__device__ inline short f2bf(float f) {
    union { float f; unsigned u; } q; q.f = f;
    unsigned r = (q.u + 0x7fffu + ((q.u >> 16) & 1u)) >> 16;
    return (short)r;
}

__device__ inline void block_sync() {
    asm volatile("s_waitcnt lgkmcnt(0)" ::: "memory");
    __builtin_amdgcn_s_barrier();
}

__global__ __launch_bounds__(512)
void elman_kernel(const float* __restrict__ x,
                  const float* __restrict__ a0,
                  const float* __restrict__ U_w,
                  const float* __restrict__ U_b,
                  const float* __restrict__ W_w,
                  const float* __restrict__ W_b,
                  const float* __restrict__ V_w,
                  const float* __restrict__ V_b,
                  float* __restrict__ out)
{
    __shared__ __align__(16) short a_lds[2][16][A_STRIDE];
    __shared__ __align__(16) short x_lds[8][16][X_STRIDE];

    const int tid  = threadIdx.x;
    const int w    = tid >> 6;       // wave 0..7
    const int l    = tid & 63;       // lane
    const int b0   = blockIdx.x * 16;

    const int lrow = l & 15;         // A-frag row / B-frag col / C col
    const int lk8  = (l >> 4) * 8;   // k base for A/B frags (8 bf16 per lane)
    const int c    = w * 16 + lrow;  // this wave's global output column

    // ---- preload step-invariant B-operand fragments (W, U) into registers ----
    bf16x8 wfrag0, wfrag1, wfrag2, wfrag3, ufrag;
    #pragma unroll
    for (int j = 0; j < 8; ++j) {
        wfrag0[j] = f2bf(W_w[(0  + lk8 + j) * S_DIM + c]);
        wfrag1[j] = f2bf(W_w[(32 + lk8 + j) * S_DIM + c]);
        wfrag2[j] = f2bf(W_w[(64 + lk8 + j) * S_DIM + c]);
        wfrag3[j] = f2bf(W_w[(96 + lk8 + j) * S_DIM + c]);
        int k = lk8 + j;
        ufrag[j] = (k < N_IN) ? f2bf(U_w[k * S_DIM + c]) : (short)0;
    }
    const float bias = W_b[c] + U_b[c];

    // ---- zero the x_lds pad region (k = 12..31), never rewritten ----
    // 8 bufs * 16 rows * 20 elems = 2560 shorts, 512 threads * 5
    for (int i = tid; i < 8 * 16 * 20; i += 512) {
        int buf = i / 320, rem = i % 320;
        x_lds[buf][rem / 20][12 + rem % 20] = 0;
    }

    // ---- stage a0 into a_lds[0] (bf16) ----
    {
        int r = tid >> 5, k4 = tid & 31;  // 512 threads: 16 rows x 32 quads
        const float4 v = *(const float4*)&a0[(size_t)(b0 + r) * S_DIM + k4 * 4];
        short* dst = &a_lds[0][r][k4 * 4];
        dst[0] = f2bf(v.x); dst[1] = f2bf(v.y); dst[2] = f2bf(v.z); dst[3] = f2bf(v.w);
    }

    // ---- prologue: stage x_0..x_5 into ring bufs 0..5 ----
    const int stage_r = l / 3, stage_p = l % 3;   // 48 lanes: 16 rows x 3 float4
    if (w < 6 && l < 48) {
        const float4 v = *(const float4*)&x[((size_t)(b0 + stage_r) * L_SEQ + w) * N_IN + stage_p * 4];
        short* dst = &x_lds[w][stage_r][stage_p * 4];
        dst[0] = f2bf(v.x); dst[1] = f2bf(v.y); dst[2] = f2bf(v.z); dst[3] = f2bf(v.w);
    }
    block_sync();

    // ---- main recurrence ----
    float4 xstage;  // in-flight x prefetch (held ~5 steps across barriers)
    for (int t = 0; t < L_SEQ; ++t) {
        const int p = t & 1;

        // A-operand fragments for this step
        const short* abase = &a_lds[p][lrow][0];
        bf16x8 af0 = *(const bf16x8*)(abase + lk8);
        bf16x8 af1 = *(const bf16x8*)(abase + 32 + lk8);
        bf16x8 af2 = *(const bf16x8*)(abase + 64 + lk8);
        bf16x8 af3 = *(const bf16x8*)(abase + 96 + lk8);
        bf16x8 xf  = *(const bf16x8*)(&x_lds[t & 7][lrow][lk8]);

        // issue x prefetch for step t+6 (one wave per step; stays in VGPRs)
        if (w == ((t + 6) & 7) && (t + 6) < L_SEQ && l < 48) {
            xstage = *(const float4*)&x[((size_t)(b0 + stage_r) * L_SEQ + (t + 6)) * N_IN + stage_p * 4];
        }

        f32x4 acc = {bias, bias, bias, bias};
        acc = __builtin_amdgcn_mfma_f32_16x16x32_bf16(af0, wfrag0, acc, 0, 0, 0);
        acc = __builtin_amdgcn_mfma_f32_16x16x32_bf16(af1, wfrag1, acc, 0, 0, 0);
        acc = __builtin_amdgcn_mfma_f32_16x16x32_bf16(af2, wfrag2, acc, 0, 0, 0);
        acc = __builtin_amdgcn_mfma_f32_16x16x32_bf16(af3, wfrag3, acc, 0, 0, 0);
        acc = __builtin_amdgcn_mfma_f32_16x16x32_bf16(xf,  ufrag,  acc, 0, 0, 0);

        // write previously-prefetched x_{t+1} into the ring (loaded 5 steps ago)
        if (w == ((t + 1) & 7) && (t + 1) >= 6 && (t + 1) < L_SEQ && l < 48) {
            short* dst = &x_lds[(t + 1) & 7][stage_r][stage_p * 4];
            dst[0] = f2bf(xstage.x); dst[1] = f2bf(xstage.y);
            dst[2] = f2bf(xstage.z); dst[3] = f2bf(xstage.w);
        }

        // relu + store a_{t+1} (C layout: col=lrow, rows (l>>4)*4+j)
        #pragma unroll
        for (int j = 0; j < 4; ++j) {
            float v = fmaxf(acc[j], 0.f);
            a_lds[p ^ 1][(l >> 4) * 4 + j][c] = f2bf(v);
        }
        block_sync();
    }

    // ---- epilogue: y = a_L @ V_w + V_b (final a is in a_lds[0]) ----
    if (w == 0) {
        bf16x8 vf0, vf1, vf2, vf3;
        #pragma unroll
        for (int j = 0; j < 8; ++j) {
            int cc = lrow;
            vf0[j] = (cc < M_OUT) ? f2bf(V_w[(0  + lk8 + j) * M_OUT + cc]) : (short)0;
            vf1[j] = (cc < M_OUT) ? f2bf(V_w[(32 + lk8 + j) * M_OUT + cc]) : (short)0;
            vf2[j] = (cc < M_OUT) ? f2bf(V_w[(64 + lk8 + j) * M_OUT + cc]) : (short)0;
            vf3[j] = (cc < M_OUT) ? f2bf(V_w[(96 + lk8 + j) * M_OUT + cc]) : (short)0;
        }
        const short* abase = &a_lds[0][lrow][0];
        bf16x8 af0 = *(const bf16x8*)(abase + lk8);
        bf16x8 af1 = *(const bf16x8*)(abase + 32 + lk8);
        bf16x8 af2 = *(const bf16x8*)(abase + 64 + lk8);
        bf16x8 af3 = *(const bf16x8*)(abase + 96 + lk8);
        f32x4 acc = {0.f, 0.f, 0.f, 0.f};
        acc = __builtin_amdgcn_mfma_f32_16x16x32_bf16(af0, vf0, acc, 0, 0, 0);
        acc = __builtin_amdgcn_mfma_f32_16x16x32_bf16(af1, vf1, acc, 0, 0, 0);
        acc = __builtin_amdgcn_mfma_f32_16x16x32_bf16(af2, vf2, acc, 0, 0, 0);
        acc = __builtin_amdgcn_mfma_f32_16x16x32_bf16(af3, vf3, acc, 0, 0, 0);
        if (lrow < M_OUT) {
            const float vb = V_b[lrow];
            #pragma unroll
            for (int j = 0; j < 4; ++j) {
                out[(size_t)(b0 + (l >> 4) * 4 + j) * M_OUT + lrow] = acc[j] + vb;
            }
        }
    }
}

extern "C" void kernel_launch(void* const* d_in, const int* in_sizes, int n_in,
                              void* d_out, int out_size, void* d_ws, size_t ws_size,
                              hipStream_t stream) {
    const float* x   = (const float*)d_in[0];
    const float* a0  = (const float*)d_in[1];
    const float* U_w = (const float*)d_in[2];
    const float* U_b = (const float*)d_in[3];
    const float* W_w = (const float*)d_in[4];
    const float* W_b = (const float*)d_in[5];
    const float* V_w = (const float*)d_in[6];
    const float* V_b = (const float*)d_in[7];
    float* out = (float*)d_out;

    hipLaunchKernelGGL(elman_kernel, dim3(4096 / 16), dim3(512), 0, stream,
                       x, a0, U_w, U_b, W_w, W_b, V_w, V_b, out);
}